// Round 1
// baseline (1616.766 us; speedup 1.0000x reference)
//
#include <hip/hip_runtime.h>
#include <math.h>

#define NN   50000
#define NE   800000
#define NET  850000      // edges + self loops
#define NG   64
#define KIN  500
#define NEG  0.2f

// ---------------- CSR build (by dst) ----------------
__global__ void k_deg(const int* __restrict__ ei, int* __restrict__ deg) {
    int e = blockIdx.x * 256 + threadIdx.x;
    if (e >= NET) return;
    int dst = (e < NE) ? ei[NE + e] : (e - NE);
    atomicAdd(&deg[dst], 1);
}

__global__ void k_scan_part(const int* __restrict__ deg, int* __restrict__ part) {
    __shared__ int s[256];
    int t = threadIdx.x;
    int i = blockIdx.x * 256 + t;
    s[t] = (i < NN) ? deg[i] : 0;
    __syncthreads();
    for (int off = 128; off > 0; off >>= 1) {
        if (t < off) s[t] += s[t + off];
        __syncthreads();
    }
    if (t == 0) part[blockIdx.x] = s[0];
}

__global__ void k_scan_top(int* __restrict__ part, int nb) {
    __shared__ int s[256];
    int t = threadIdx.x;
    int v = (t < nb) ? part[t] : 0;
    s[t] = v;
    __syncthreads();
    for (int off = 1; off < 256; off <<= 1) {
        int a = (t >= off) ? s[t - off] : 0;
        __syncthreads();
        s[t] += a;
        __syncthreads();
    }
    if (t < nb) part[t] = s[t] - v;   // exclusive
}

__global__ void k_scan_apply(const int* __restrict__ deg, const int* __restrict__ part,
                             int* __restrict__ rowptr) {
    __shared__ int s[256];
    int t = threadIdx.x;
    int i = blockIdx.x * 256 + t;
    int v = (i < NN) ? deg[i] : 0;
    s[t] = v;
    __syncthreads();
    for (int off = 1; off < 256; off <<= 1) {
        int a = (t >= off) ? s[t - off] : 0;
        __syncthreads();
        s[t] += a;
        __syncthreads();
    }
    if (i < NN) rowptr[i] = part[blockIdx.x] + s[t] - v;
    if (i == 0) rowptr[NN] = NET;
}

__global__ void k_fill(const int* __restrict__ ei, const int* __restrict__ rowptr,
                       int* __restrict__ cursor, int* __restrict__ csr) {
    int e = blockIdx.x * 256 + threadIdx.x;
    if (e >= NET) return;
    int src, dst;
    if (e < NE) { src = ei[e]; dst = ei[NE + e]; }
    else        { src = dst = e - NE; }
    int pos = atomicAdd(&cursor[dst], 1);
    csr[rowptr[dst] + pos] = src;
}

// ---------------- fp32 GEMM, 64x64 tile, 4x4 micro-tile, fused a-vector epilogue -----
// Computes H = A[NN,K] @ W[K, HEADS*64] (block covers one 64-col head),
// plus al_s[row,h] = dot(Hrow_head, a_s_head), al_d likewise.
template <int K, int LDA, int LDW, int HEADS>
__global__ __launch_bounds__(256) void k_gemm(
    const float* __restrict__ A, const float* __restrict__ W,
    const float* __restrict__ a_s, const float* __restrict__ a_d,
    float* __restrict__ Hout, float* __restrict__ als, float* __restrict__ ald)
{
    __shared__ __align__(16) float xs[32][68];   // [k][m] transposed A tile, +4 pad keeps 16B align
    __shared__ __align__(16) float wsh[32][64];  // [k][n]
    const int FOUT = HEADS * 64;
    const int h    = blockIdx.x;         // head / column tile
    const int row0 = blockIdx.y * 64;
    const int t    = threadIdx.x;
    const int tx   = t & 15;             // column group
    const int ty   = t >> 4;             // row group

    float acc[4][4] = {};
    const float4 av_s = *(const float4*)&a_s[h * 64 + tx * 4];
    const float4 av_d = *(const float4*)&a_d[h * 64 + tx * 4];

    const int NT = (K + 31) / 32;
    for (int kt = 0; kt < NT; kt++) {
        int k0 = kt * 32;
#pragma unroll
        for (int i = 0; i < 8; i++) {          // A tile: 64 rows x 32 k, stored transposed
            int idx = t + i * 256;
            int kk = idx & 31, mm = idx >> 5;
            int row = row0 + mm, kg = k0 + kk;
            float v = 0.f;
            if (row < NN && kg < K) v = A[(size_t)row * LDA + kg];
            xs[kk][mm] = v;
        }
#pragma unroll
        for (int i = 0; i < 8; i++) {          // W tile: 32 k x 64 n
            int idx = t + i * 256;
            int kk = idx >> 6, nn = idx & 63;
            int kg = k0 + kk;
            float v = 0.f;
            if (kg < K) v = W[(size_t)kg * LDW + h * 64 + nn];
            wsh[kk][nn] = v;
        }
        __syncthreads();
#pragma unroll
        for (int k = 0; k < 32; k++) {
            const float4 a4 = *(const float4*)&xs[k][ty * 4];
            const float4 b4 = *(const float4*)&wsh[k][tx * 4];
            float av[4] = {a4.x, a4.y, a4.z, a4.w};
            float bv[4] = {b4.x, b4.y, b4.z, b4.w};
#pragma unroll
            for (int i = 0; i < 4; i++)
#pragma unroll
                for (int j = 0; j < 4; j++)
                    acc[i][j] += av[i] * bv[j];
        }
        __syncthreads();
    }

    // write H tile
#pragma unroll
    for (int i = 0; i < 4; i++) {
        int row = row0 + ty * 4 + i;
        if (row < NN) {
            float4 v = make_float4(acc[i][0], acc[i][1], acc[i][2], acc[i][3]);
            *(float4*)&Hout[(size_t)row * FOUT + h * 64 + tx * 4] = v;
        }
    }
    // fused per-row attention logits (reduce over the 16 tx lanes of each 16-lane group)
#pragma unroll
    for (int i = 0; i < 4; i++) {
        float ps = acc[i][0] * av_s.x + acc[i][1] * av_s.y + acc[i][2] * av_s.z + acc[i][3] * av_s.w;
        float pd = acc[i][0] * av_d.x + acc[i][1] * av_d.y + acc[i][2] * av_d.z + acc[i][3] * av_d.w;
#pragma unroll
        for (int off = 1; off < 16; off <<= 1) {
            ps += __shfl_xor(ps, off);
            pd += __shfl_xor(pd, off);
        }
        int row = row0 + ty * 4 + i;
        if (tx == 0 && row < NN) {
            als[(size_t)row * HEADS + h] = ps;
            ald[(size_t)row * HEADS + h] = pd;
        }
    }
}

// ---------------- attention-weighted aggregation: one wave per (dst, head) ----------
template <int HEADS>
__global__ __launch_bounds__(256) void k_agg(
    const int* __restrict__ rowptr, const int* __restrict__ csr,
    const float* __restrict__ Hf, const float* __restrict__ als,
    const float* __restrict__ ald, const float* __restrict__ bias,
    float* __restrict__ Out)
{
    const int F = HEADS * 64;
    int w = threadIdx.x >> 6, lane = threadIdx.x & 63;
    int gw = blockIdx.x * 4 + w;
    int dst = gw / HEADS, head = gw % HEADS;
    if (dst >= NN) return;

    int beg = rowptr[dst], end = rowptr[dst + 1];
    float adst = ald[(size_t)dst * HEADS + head];

    int   i    = beg;
    int   src  = csr[i];
    float as_v = als[(size_t)src * HEADS + head];
    float xv   = Hf[(size_t)src * F + head * 64 + lane];

    float m = -1e30f, s = 0.f, acc = 0.f;
    while (true) {
        int inext = i + 1;
        bool more = inext < end;
        int src2 = 0; float as2 = 0.f, xv2 = 0.f;
        if (more) {                                // 1-deep prefetch to hide gather latency
            src2 = csr[inext];
            as2  = als[(size_t)src2 * HEADS + head];
            xv2  = Hf[(size_t)src2 * F + head * 64 + lane];
        }
        float e = as_v + adst;
        e = (e > 0.f) ? e : NEG * e;               // leaky_relu
        float mn = fmaxf(m, e);
        float sc = __expf(m - mn);                 // first iter: exp(-1e30)=0
        float pr = __expf(e - mn);
        s   = s * sc + pr;
        acc = acc * sc + pr * xv;
        m = mn;
        if (!more) break;
        i = inext; as_v = as2; xv = xv2;
    }
    float o = acc / (s + 1e-16f) + bias[head * 64 + lane];
    Out[(size_t)dst * F + head * 64 + lane] = (o > 0.f) ? o : 0.f;
}

// ---------------- global mean pool (atomics into 64x64) ----------------
__global__ void k_pool(const float* __restrict__ out2, const int* __restrict__ batch,
                       float* __restrict__ pooled, float* __restrict__ cnt)
{
    int idx = blockIdx.x * 256 + threadIdx.x;     // over NN*64
    if (idx >= NN * 64) return;
    int n = idx >> 6, c = idx & 63;
    int g = batch[n];
    atomicAdd(&pooled[g * 64 + c], out2[idx]);
    if (c == 0) atomicAdd(&cnt[g], 1.0f);
}

// ---------------- final linear [64,64]@[64,2]+b ----------------
__global__ void k_final(const float* __restrict__ pooled, const float* __restrict__ cnt,
                        const float* __restrict__ Wl, const float* __restrict__ bl,
                        float* __restrict__ out)
{
    int g = blockIdx.x, c = threadIdx.x;          // 64 threads = 1 wave
    float p = pooled[g * 64 + c] / fmaxf(cnt[g], 1.0f);
    float r0 = p * Wl[c * 2 + 0];
    float r1 = p * Wl[c * 2 + 1];
#pragma unroll
    for (int off = 32; off > 0; off >>= 1) {
        r0 += __shfl_xor(r0, off);
        r1 += __shfl_xor(r1, off);
    }
    if (c == 0) {
        out[g * 2 + 0] = r0 + bl[0];
        out[g * 2 + 1] = r1 + bl[1];
    }
}

extern "C" void kernel_launch(void* const* d_in, const int* in_sizes, int n_in,
                              void* d_out, int out_size, void* d_ws, size_t ws_size,
                              hipStream_t stream)
{
    const float* x    = (const float*)d_in[0];
    const int*   ei   = (const int*)  d_in[1];
    const int*   batch= (const int*)  d_in[2];
    const float* W1   = (const float*)d_in[3];
    const float* as1  = (const float*)d_in[4];
    const float* ad1  = (const float*)d_in[5];
    const float* b1   = (const float*)d_in[6];
    const float* W2   = (const float*)d_in[7];
    const float* as2  = (const float*)d_in[8];
    const float* ad2  = (const float*)d_in[9];
    const float* b2   = (const float*)d_in[10];
    const float* Wl   = (const float*)d_in[11];
    const float* bl   = (const float*)d_in[12];
    float* out = (float*)d_out;

    // workspace carve-up (all 4-byte units, 16B-aligned chunks)
    int* p = (int*)d_ws;
    int*   deg    = p;          p += 50048;
    int*   cursor = p;          p += 50048;
    float* pooled = (float*)p;  p += 4096;
    float* cnt    = (float*)p;  p += 64;
    size_t zero_bytes = (size_t)((char*)p - (char*)d_ws);   // zeroed every call
    int*   rowptr = p;          p += 50064;
    int*   csr    = p;          p += 850048;
    float* h1     = (float*)p;  p += NN * 256;
    float* out1   = (float*)p;  p += NN * 256;
    float* al1s   = (float*)p;  p += 200064;
    float* al1d   = (float*)p;  p += 200064;
    int*   part   = p;          p += 256;
    // layer-2 buffers alias layer-1's h1 region (free by then)
    float* h2   = h1;
    float* out2 = h1 + (size_t)NN * 64;
    float* al2s = al1s;
    float* al2d = al1d;

    hipMemsetAsync(d_ws, 0, zero_bytes, stream);

    // CSR build
    k_deg       <<<(NET + 255) / 256, 256, 0, stream>>>(ei, deg);
    k_scan_part <<<196, 256, 0, stream>>>(deg, part);
    k_scan_top  <<<1,   256, 0, stream>>>(part, 196);
    k_scan_apply<<<196, 256, 0, stream>>>(deg, part, rowptr);
    k_fill      <<<(NET + 255) / 256, 256, 0, stream>>>(ei, rowptr, cursor, csr);

    // layer 1: H=4, C=64
    k_gemm<KIN, KIN, 256, 4><<<dim3(4, (NN + 63) / 64), 256, 0, stream>>>(
        x, W1, as1, ad1, h1, al1s, al1d);
    k_agg<4><<<NN, 256, 0, stream>>>(rowptr, csr, h1, al1s, al1d, b1, out1);

    // layer 2: H=1, C=64
    k_gemm<256, 256, 64, 1><<<dim3(1, (NN + 63) / 64), 256, 0, stream>>>(
        out1, W2, as2, ad2, h2, al2s, al2d);
    k_agg<1><<<(NN + 3) / 4, 256, 0, stream>>>(rowptr, csr, h2, al2s, al2d, b2, out2);

    // pooling + classifier
    k_pool <<<(NN * 64 + 255) / 256, 256, 0, stream>>>(out2, batch, pooled, cnt);
    k_final<<<NG, 64, 0, stream>>>(pooled, cnt, Wl, bl, out);
}

// Round 2
// 775.924 us; speedup vs baseline: 2.0837x; 2.0837x over previous
//
#include <hip/hip_runtime.h>
#include <math.h>

#define NN   50000
#define NE   800000
#define NET  850000      // edges + self loops
#define NG   64
#define KIN  500
#define NEG  0.2f

typedef unsigned short ushort_t;
typedef __attribute__((ext_vector_type(8))) short bf8_t;   // 8 bf16 in 4 VGPRs
typedef __attribute__((ext_vector_type(4))) float f4_t;

__device__ __forceinline__ float bf2f(ushort_t u) {
    unsigned v = ((unsigned)u) << 16;
    return __builtin_bit_cast(float, v);
}
__device__ __forceinline__ ushort_t f2bf(float f) {
    unsigned b = __builtin_bit_cast(unsigned, f);
    unsigned r = (b + 0x7FFFu + ((b >> 16) & 1u)) >> 16;   // RNE
    return (ushort_t)r;
}

#define GLOAD_LDS(g, l)                                                        \
    __builtin_amdgcn_global_load_lds(                                          \
        (const __attribute__((address_space(1))) unsigned int*)(g),            \
        (__attribute__((address_space(3))) unsigned int*)(l), 16, 0, 0)

// ---------------- CSR build (by dst) ----------------
__global__ void k_deg(const int* __restrict__ ei, int* __restrict__ deg) {
    int e = blockIdx.x * 256 + threadIdx.x;
    if (e >= NET) return;
    int dst = (e < NE) ? ei[NE + e] : (e - NE);
    atomicAdd(&deg[dst], 1);
}

__global__ void k_scan_part(const int* __restrict__ deg, int* __restrict__ part) {
    __shared__ int s[256];
    int t = threadIdx.x;
    int i = blockIdx.x * 256 + t;
    s[t] = (i < NN) ? deg[i] : 0;
    __syncthreads();
    for (int off = 128; off > 0; off >>= 1) {
        if (t < off) s[t] += s[t + off];
        __syncthreads();
    }
    if (t == 0) part[blockIdx.x] = s[0];
}

__global__ void k_scan_top(int* __restrict__ part, int nb) {
    __shared__ int s[256];
    int t = threadIdx.x;
    int v = (t < nb) ? part[t] : 0;
    s[t] = v;
    __syncthreads();
    for (int off = 1; off < 256; off <<= 1) {
        int a = (t >= off) ? s[t - off] : 0;
        __syncthreads();
        s[t] += a;
        __syncthreads();
    }
    if (t < nb) part[t] = s[t] - v;   // exclusive
}

__global__ void k_scan_apply(const int* __restrict__ deg, const int* __restrict__ part,
                             int* __restrict__ rowptr) {
    __shared__ int s[256];
    int t = threadIdx.x;
    int i = blockIdx.x * 256 + t;
    int v = (i < NN) ? deg[i] : 0;
    s[t] = v;
    __syncthreads();
    for (int off = 1; off < 256; off <<= 1) {
        int a = (t >= off) ? s[t - off] : 0;
        __syncthreads();
        s[t] += a;
        __syncthreads();
    }
    if (i < NN) rowptr[i] = part[blockIdx.x] + s[t] - v;
    if (i == 0) rowptr[NN] = NET;
}

__global__ void k_fill(const int* __restrict__ ei, const int* __restrict__ rowptr,
                       int* __restrict__ cursor, int* __restrict__ csr) {
    int e = blockIdx.x * 256 + threadIdx.x;
    if (e >= NET) return;
    int src, dst;
    if (e < NE) { src = ei[e]; dst = ei[NE + e]; }
    else        { src = dst = e - NE; }
    int pos = atomicAdd(&cursor[dst], 1);
    csr[rowptr[dst] + pos] = src;
}

// ---------------- bf16 cast kernels ----------------
__global__ void k_cast_x(const float* __restrict__ x, ushort_t* __restrict__ xb) {
    int idx = blockIdx.x * 256 + threadIdx.x;     // over 50048*128 float4 groups
    if (idx >= 50048 * 128) return;
    int row = idx >> 7, k4 = (idx & 127) * 4;
    ushort4 o = make_ushort4(0, 0, 0, 0);
    if (row < NN && k4 < KIN) {
        float4 v = *(const float4*)&x[(size_t)row * KIN + k4];
        o.x = f2bf(v.x); o.y = f2bf(v.y); o.z = f2bf(v.z); o.w = f2bf(v.w);
    }
    *(ushort4*)&xb[(size_t)idx * 4] = o;
}

template <int KSRC, int KPAD, int NOUT>
__global__ void k_cast_wt(const float* __restrict__ W, ushort_t* __restrict__ Wt) {
    int idx = blockIdx.x * 256 + threadIdx.x;     // over NOUT*KPAD
    if (idx >= NOUT * KPAD) return;
    int n = idx / KPAD, k = idx - n * KPAD;
    float v = (k < KSRC) ? W[(size_t)k * NOUT + n] : 0.f;
    Wt[idx] = f2bf(v);
}

// ---------------- bf16 MFMA GEMM: H = A @ W, fused attention-logit epilogue ----
// A: [Mpad][LDA] bf16, Wt: [FOUT][K] bf16 (pre-transposed W).
// Block tile BM x BN, 4 waves each computing 64x64 via 4x4 grid of 16x16x32 MFMAs.
template <int K, int LDA, int BM, int BN, int WM, int FOUT, int HEADS>
__global__ __launch_bounds__(256) void k_mfma(
    const ushort_t* __restrict__ A, const ushort_t* __restrict__ Wt,
    const float* __restrict__ a_s, const float* __restrict__ a_d,
    ushort_t* __restrict__ Hb, float* __restrict__ als, float* __restrict__ ald)
{
    __shared__ __align__(16) ushort_t lA[BM * 32];
    __shared__ __align__(16) ushort_t lB[BN * 32];
    const int t    = threadIdx.x;
    const int row0 = blockIdx.y * BM;
    const int n0   = blockIdx.x * BN;
    const int ww   = t >> 6, lane = t & 63;
    const int wm   = ww % WM, wn = ww / WM;
    const int lrow = lane & 15, lq = lane >> 4;   // quad

    f4_t acc[4][4] = {};

    for (int k0 = 0; k0 < K; k0 += 32) {
#pragma unroll
        for (int i = 0; i < BM / 64; i++) {       // A tile: BM rows x 32 k
            int c = i * 256 + t;
            int row = c >> 2, kq = c & 3;
            const ushort_t* gp = A + (size_t)(row0 + row) * LDA + k0 + kq * 8;
            GLOAD_LDS(gp, &lA[c * 8]);
        }
#pragma unroll
        for (int i = 0; i < BN / 64; i++) {       // B tile: BN cols x 32 k
            int c = i * 256 + t;
            int row = c >> 2, kq = c & 3;
            const ushort_t* gp = Wt + (size_t)(n0 + row) * K + k0 + kq * 8;
            GLOAD_LDS(gp, &lB[c * 8]);
        }
        __syncthreads();
        bf8_t af[4], bfr[4];
#pragma unroll
        for (int i = 0; i < 4; i++)
            af[i] = *(const bf8_t*)&lA[(wm * 64 + i * 16 + lrow) * 32 + lq * 8];
#pragma unroll
        for (int j = 0; j < 4; j++)
            bfr[j] = *(const bf8_t*)&lB[(wn * 64 + j * 16 + lrow) * 32 + lq * 8];
#pragma unroll
        for (int i = 0; i < 4; i++)
#pragma unroll
            for (int j = 0; j < 4; j++)
                acc[i][j] = __builtin_amdgcn_mfma_f32_16x16x32_bf16(af[i], bfr[j], acc[i][j], 0, 0, 0);
        __syncthreads();
    }

    // epilogue: wave's 64 cols = exactly one head (64-wide, 64-aligned)
    const int head = (n0 + wn * 64) >> 6;
    float as4[4], ad4[4];
#pragma unroll
    for (int j = 0; j < 4; j++) {
        as4[j] = a_s[head * 64 + j * 16 + lrow];
        ad4[j] = a_d[head * 64 + j * 16 + lrow];
    }
#pragma unroll
    for (int i = 0; i < 4; i++) {
#pragma unroll
        for (int r = 0; r < 4; r++) {
            int row = row0 + wm * 64 + i * 16 + lq * 4 + r;
            float v0 = acc[i][0][r], v1 = acc[i][1][r], v2 = acc[i][2][r], v3 = acc[i][3][r];
            if (row < NN) {
                size_t base = (size_t)row * FOUT + n0 + wn * 64 + lrow;
                Hb[base +  0] = f2bf(v0);
                Hb[base + 16] = f2bf(v1);
                Hb[base + 32] = f2bf(v2);
                Hb[base + 48] = f2bf(v3);
            }
            float ps = v0 * as4[0] + v1 * as4[1] + v2 * as4[2] + v3 * as4[3];
            float pd = v0 * ad4[0] + v1 * ad4[1] + v2 * ad4[2] + v3 * ad4[3];
#pragma unroll
            for (int off = 1; off < 16; off <<= 1) {
                ps += __shfl_xor(ps, off);
                pd += __shfl_xor(pd, off);
            }
            if (lrow == 0 && row < NN) {
                als[(size_t)row * HEADS + head] = ps;
                ald[(size_t)row * HEADS + head] = pd;
            }
        }
    }
}

// ---------------- attention-weighted aggregation: one wave per (dst, head) ----------
template <int HEADS, int F, bool OUTBF>
__global__ __launch_bounds__(256) void k_agg(
    const int* __restrict__ rowptr, const int* __restrict__ csr,
    const ushort_t* __restrict__ Hb, const float* __restrict__ als,
    const float* __restrict__ ald, const float* __restrict__ bias,
    ushort_t* __restrict__ OutB, float* __restrict__ OutF)
{
    int w = threadIdx.x >> 6, lane = threadIdx.x & 63;
    int gw = blockIdx.x * 4 + w;
    int dst = gw / HEADS, head = gw % HEADS;
    if (dst >= NN) return;

    int beg = rowptr[dst], end = rowptr[dst + 1];
    float adst = ald[(size_t)dst * HEADS + head];

    int   i    = beg;
    float as_v = als[(size_t)csr[i] * HEADS + head];
    float xv   = bf2f(Hb[(size_t)csr[i] * F + head * 64 + lane]);

    float m = -1e30f, s = 0.f, acc = 0.f;
    while (true) {
        int inext = i + 1;
        bool more = inext < end;
        float as2 = 0.f, xv2 = 0.f;
        if (more) {                                // 1-deep prefetch
            int src2 = csr[inext];
            as2 = als[(size_t)src2 * HEADS + head];
            xv2 = bf2f(Hb[(size_t)src2 * F + head * 64 + lane]);
        }
        float e = as_v + adst;
        e = (e > 0.f) ? e : NEG * e;               // leaky_relu
        float mn = fmaxf(m, e);
        float sc = __expf(m - mn);                 // first iter: exp(-inf)=0
        float pr = __expf(e - mn);
        s   = s * sc + pr;
        acc = acc * sc + pr * xv;
        m = mn;
        if (!more) break;
        i = inext; as_v = as2; xv = xv2;
    }
    float o = acc / (s + 1e-16f) + bias[head * 64 + lane];
    o = (o > 0.f) ? o : 0.f;                       // relu
    if (OUTBF) OutB[(size_t)dst * F + head * 64 + lane] = f2bf(o);
    else       OutF[(size_t)dst * F + head * 64 + lane] = o;
}

// ---------------- fused mean-pool (sorted batch, no atomics) + classifier --------
__global__ void k_pool_final(const float* __restrict__ out2, const int* __restrict__ batch,
                             const float* __restrict__ Wl, const float* __restrict__ bl,
                             float* __restrict__ out)
{
    int g = blockIdx.x;
    int lo, hi;
    { int a = 0, b = NN; while (a < b) { int mm = (a + b) >> 1; if (batch[mm] < g) a = mm + 1; else b = mm; } lo = a; }
    { int a = lo, b = NN; while (a < b) { int mm = (a + b) >> 1; if (batch[mm] < g + 1) a = mm + 1; else b = mm; } hi = a; }
    int t = threadIdx.x, c = t & 63, r = t >> 6;
    float s = 0.f;
    for (int n = lo + r; n < hi; n += 4) s += out2[(size_t)n * 64 + c];
    __shared__ float red[256];
    red[t] = s;
    __syncthreads();
    if (t < 64) {
        float p = red[t] + red[t + 64] + red[t + 128] + red[t + 192];
        int cntv = hi - lo;
        p /= (float)(cntv > 0 ? cntv : 1);
        float r0 = p * Wl[t * 2 + 0];
        float r1 = p * Wl[t * 2 + 1];
#pragma unroll
        for (int off = 32; off > 0; off >>= 1) {
            r0 += __shfl_xor(r0, off);
            r1 += __shfl_xor(r1, off);
        }
        if (t == 0) {
            out[g * 2 + 0] = r0 + bl[0];
            out[g * 2 + 1] = r1 + bl[1];
        }
    }
}

extern "C" void kernel_launch(void* const* d_in, const int* in_sizes, int n_in,
                              void* d_out, int out_size, void* d_ws, size_t ws_size,
                              hipStream_t stream)
{
    const float* x    = (const float*)d_in[0];
    const int*   ei   = (const int*)  d_in[1];
    const int*   batch= (const int*)  d_in[2];
    const float* W1   = (const float*)d_in[3];
    const float* as1  = (const float*)d_in[4];
    const float* ad1  = (const float*)d_in[5];
    const float* b1   = (const float*)d_in[6];
    const float* W2   = (const float*)d_in[7];
    const float* as2  = (const float*)d_in[8];
    const float* ad2  = (const float*)d_in[9];
    const float* b2   = (const float*)d_in[10];
    const float* Wl   = (const float*)d_in[11];
    const float* bl   = (const float*)d_in[12];
    float* out = (float*)d_out;

    // ---- workspace carve-up ----
    int*   deg    = (int*)d_ws;                       // 50048
    int*   cursor = deg + 50048;                      // 50048
    int*   part   = cursor + 50048;                   // 256
    int*   rowptr = part + 256;                       // 50064
    int*   csr    = rowptr + 50064;                   // 850048
    ushort_t* xb  = (ushort_t*)(csr + 850048);        // 50048*512
    ushort_t* Wt1 = xb + (size_t)50048 * 512;         // 256*512
    ushort_t* Wt2 = Wt1 + 131072;                     // 64*256
    ushort_t* h1b = Wt2 + 16384;                      // 50000*256
    float* al1s   = (float*)(h1b + (size_t)50000 * 256); // 200000
    float* al1d   = al1s + 200000;
    float* al2s   = al1d + 200000;                    // 50000
    float* al2d   = al2s + 50000;
    // aliases inside xb (dead after GEMM1):
    ushort_t* out1b = xb;                             // 50176*256 = 12.85M ushorts
    ushort_t* h2b   = xb + 13000000;                  // 50000*64  = 3.2M ushorts
    float*    out2  = (float*)(xb + 16400000);        // 50000*64 floats

    hipMemsetAsync(deg, 0, 2 * 50048 * sizeof(int), stream);   // deg + cursor

    // CSR build
    k_deg       <<<(NET + 255) / 256, 256, 0, stream>>>(ei, deg);
    k_scan_part <<<196, 256, 0, stream>>>(deg, part);
    k_scan_top  <<<1,   256, 0, stream>>>(part, 196);
    k_scan_apply<<<196, 256, 0, stream>>>(deg, part, rowptr);
    k_fill      <<<(NET + 255) / 256, 256, 0, stream>>>(ei, rowptr, cursor, csr);

    // bf16 casts
    k_cast_x<<<(50048 * 128 + 255) / 256, 256, 0, stream>>>(x, xb);
    k_cast_wt<500, 512, 256><<<(256 * 512 + 255) / 256, 256, 0, stream>>>(W1, Wt1);
    k_cast_wt<256, 256, 64> <<<(64 * 256 + 255) / 256, 256, 0, stream>>>(W2, Wt2);

    // layer 1: M=50048(pad), N=256, K=512(pad); tile 128x128, 2x2 waves
    k_mfma<512, 512, 128, 128, 2, 256, 4><<<dim3(2, 391), 256, 0, stream>>>(
        xb, Wt1, as1, ad1, h1b, al1s, al1d);
    k_agg<4, 256, true><<<NN, 256, 0, stream>>>(rowptr, csr, h1b, al1s, al1d, b1, out1b, nullptr);
    // zero pad rows 50000..50175 of out1b for GEMM2 (after agg1; xb region reused)
    hipMemsetAsync(out1b + (size_t)50000 * 256, 0, (size_t)176 * 256 * sizeof(ushort_t), stream);

    // layer 2: M=50176(pad), N=64, K=256; tile 256x64, 4x1 waves
    k_mfma<256, 256, 256, 64, 4, 64, 1><<<dim3(1, 196), 256, 0, stream>>>(
        out1b, Wt2, as2, ad2, h2b, al2s, al2d);
    k_agg<1, 64, false><<<(NN + 3) / 4, 256, 0, stream>>>(rowptr, csr, h2b, al2s, al2d, b2, nullptr, out2);

    // fused pool + classifier
    k_pool_final<<<NG, 256, 0, stream>>>(out2, batch, Wl, bl, out);
}

// Round 3
// 496.172 us; speedup vs baseline: 3.2585x; 1.5638x over previous
//
#include <hip/hip_runtime.h>
#include <math.h>

#define NN   50000
#define NE   800000
#define NET  850000      // edges + self loops
#define NG   64
#define KIN  500
#define NEG  0.2f

typedef unsigned short ushort_t;
typedef __attribute__((ext_vector_type(8))) short bf8_t;      // 8 bf16 in 4 VGPRs
typedef __attribute__((ext_vector_type(8))) unsigned short us8_t;
typedef __attribute__((ext_vector_type(4))) float f4_t;

__device__ __forceinline__ float bf2f(ushort_t u) {
    unsigned v = ((unsigned)u) << 16;
    return __builtin_bit_cast(float, v);
}
__device__ __forceinline__ ushort_t f2bf(float f) {
    unsigned b = __builtin_bit_cast(unsigned, f);
    unsigned r = (b + 0x7FFFu + ((b >> 16) & 1u)) >> 16;   // RNE
    return (ushort_t)r;
}

#define GLOAD_LDS(g, l)                                                        \
    __builtin_amdgcn_global_load_lds(                                          \
        (const __attribute__((address_space(1))) unsigned int*)(g),            \
        (__attribute__((address_space(3))) unsigned int*)(l), 16, 0, 0)

// ---------------- CSR build (by dst) ----------------
__global__ void k_deg(const int* __restrict__ ei, int* __restrict__ deg) {
    int e = blockIdx.x * 256 + threadIdx.x;
    if (e >= NET) return;
    int dst = (e < NE) ? ei[NE + e] : (e - NE);
    atomicAdd(&deg[dst], 1);
}

__global__ void k_scan_part(const int* __restrict__ deg, int* __restrict__ part) {
    __shared__ int s[256];
    int t = threadIdx.x;
    int i = blockIdx.x * 256 + t;
    s[t] = (i < NN) ? deg[i] : 0;
    __syncthreads();
    for (int off = 128; off > 0; off >>= 1) {
        if (t < off) s[t] += s[t + off];
        __syncthreads();
    }
    if (t == 0) part[blockIdx.x] = s[0];
}

__global__ void k_scan_top(int* __restrict__ part, int nb) {
    __shared__ int s[256];
    int t = threadIdx.x;
    int v = (t < nb) ? part[t] : 0;
    s[t] = v;
    __syncthreads();
    for (int off = 1; off < 256; off <<= 1) {
        int a = (t >= off) ? s[t - off] : 0;
        __syncthreads();
        s[t] += a;
        __syncthreads();
    }
    if (t < nb) part[t] = s[t] - v;   // exclusive
}

__global__ void k_scan_apply(const int* __restrict__ deg, const int* __restrict__ part,
                             int* __restrict__ rowptr) {
    __shared__ int s[256];
    int t = threadIdx.x;
    int i = blockIdx.x * 256 + t;
    int v = (i < NN) ? deg[i] : 0;
    s[t] = v;
    __syncthreads();
    for (int off = 1; off < 256; off <<= 1) {
        int a = (t >= off) ? s[t - off] : 0;
        __syncthreads();
        s[t] += a;
        __syncthreads();
    }
    if (i < NN) rowptr[i] = part[blockIdx.x] + s[t] - v;
    if (i == 0) rowptr[NN] = NET;
}

__global__ void k_fill(const int* __restrict__ ei, const int* __restrict__ rowptr,
                       int* __restrict__ cursor, int* __restrict__ csr) {
    int e = blockIdx.x * 256 + threadIdx.x;
    if (e >= NET) return;
    int src, dst;
    if (e < NE) { src = ei[e]; dst = ei[NE + e]; }
    else        { src = dst = e - NE; }
    int pos = atomicAdd(&cursor[dst], 1);
    csr[rowptr[dst] + pos] = src;
}

// ---------------- bf16 cast kernels ----------------
__global__ void k_cast_x(const float* __restrict__ x, ushort_t* __restrict__ xb) {
    int idx = blockIdx.x * 256 + threadIdx.x;     // over 50048*128 float4 groups
    if (idx >= 50048 * 128) return;
    int row = idx >> 7, k4 = (idx & 127) * 4;
    ushort4 o = make_ushort4(0, 0, 0, 0);
    if (row < NN && k4 < KIN) {
        float4 v = *(const float4*)&x[(size_t)row * KIN + k4];
        o.x = f2bf(v.x); o.y = f2bf(v.y); o.z = f2bf(v.z); o.w = f2bf(v.w);
    }
    *(ushort4*)&xb[(size_t)idx * 4] = o;
}

template <int KSRC, int KPAD, int NOUT>
__global__ void k_cast_wt(const float* __restrict__ W, ushort_t* __restrict__ Wt) {
    int idx = blockIdx.x * 256 + threadIdx.x;     // over NOUT*KPAD
    if (idx >= NOUT * KPAD) return;
    int n = idx / KPAD, k = idx - n * KPAD;
    float v = (k < KSRC) ? W[(size_t)k * NOUT + n] : 0.f;
    Wt[idx] = f2bf(v);
}

// ---------------- bf16 MFMA GEMM: H = A @ W, fused attention-logit epilogue ----
template <int K, int LDA, int BM, int BN, int WM, int FOUT, int HEADS>
__global__ __launch_bounds__(256) void k_mfma(
    const ushort_t* __restrict__ A, const ushort_t* __restrict__ Wt,
    const float* __restrict__ a_s, const float* __restrict__ a_d,
    ushort_t* __restrict__ Hb, float* __restrict__ als, float* __restrict__ ald)
{
    __shared__ __align__(16) ushort_t lA[BM * 32];
    __shared__ __align__(16) ushort_t lB[BN * 32];
    const int t    = threadIdx.x;
    const int row0 = blockIdx.y * BM;
    const int n0   = blockIdx.x * BN;
    const int ww   = t >> 6, lane = t & 63;
    const int wm   = ww % WM, wn = ww / WM;
    const int lrow = lane & 15, lq = lane >> 4;   // quad

    f4_t acc[4][4] = {};

    for (int k0 = 0; k0 < K; k0 += 32) {
#pragma unroll
        for (int i = 0; i < BM / 64; i++) {       // A tile: BM rows x 32 k
            int c = i * 256 + t;
            int row = c >> 2, kq = c & 3;
            const ushort_t* gp = A + (size_t)(row0 + row) * LDA + k0 + kq * 8;
            GLOAD_LDS(gp, &lA[c * 8]);
        }
#pragma unroll
        for (int i = 0; i < BN / 64; i++) {       // B tile: BN cols x 32 k
            int c = i * 256 + t;
            int row = c >> 2, kq = c & 3;
            const ushort_t* gp = Wt + (size_t)(n0 + row) * K + k0 + kq * 8;
            GLOAD_LDS(gp, &lB[c * 8]);
        }
        __syncthreads();
        bf8_t af[4], bfr[4];
#pragma unroll
        for (int i = 0; i < 4; i++)
            af[i] = *(const bf8_t*)&lA[(wm * 64 + i * 16 + lrow) * 32 + lq * 8];
#pragma unroll
        for (int j = 0; j < 4; j++)
            bfr[j] = *(const bf8_t*)&lB[(wn * 64 + j * 16 + lrow) * 32 + lq * 8];
#pragma unroll
        for (int i = 0; i < 4; i++)
#pragma unroll
            for (int j = 0; j < 4; j++)
                acc[i][j] = __builtin_amdgcn_mfma_f32_16x16x32_bf16(af[i], bfr[j], acc[i][j], 0, 0, 0);
        __syncthreads();
    }

    // epilogue: wave's 64 cols = exactly one head (64-wide, 64-aligned)
    const int head = (n0 + wn * 64) >> 6;
    float as4[4], ad4[4];
#pragma unroll
    for (int j = 0; j < 4; j++) {
        as4[j] = a_s[head * 64 + j * 16 + lrow];
        ad4[j] = a_d[head * 64 + j * 16 + lrow];
    }
#pragma unroll
    for (int i = 0; i < 4; i++) {
#pragma unroll
        for (int r = 0; r < 4; r++) {
            int row = row0 + wm * 64 + i * 16 + lq * 4 + r;
            float v0 = acc[i][0][r], v1 = acc[i][1][r], v2 = acc[i][2][r], v3 = acc[i][3][r];
            if (row < NN) {
                size_t base = (size_t)row * FOUT + n0 + wn * 64 + lrow;
                Hb[base +  0] = f2bf(v0);
                Hb[base + 16] = f2bf(v1);
                Hb[base + 32] = f2bf(v2);
                Hb[base + 48] = f2bf(v3);
            }
            float ps = v0 * as4[0] + v1 * as4[1] + v2 * as4[2] + v3 * as4[3];
            float pd = v0 * ad4[0] + v1 * ad4[1] + v2 * ad4[2] + v3 * ad4[3];
#pragma unroll
            for (int off = 1; off < 16; off <<= 1) {
                ps += __shfl_xor(ps, off);
                pd += __shfl_xor(pd, off);
            }
            if (lrow == 0 && row < NN) {
                als[(size_t)row * HEADS + head] = ps;
                ald[(size_t)row * HEADS + head] = pd;
            }
        }
    }
}

// ---- layer-1 aggregation: ONE wave per dst, all 4 heads, 2 edges/iter, 16B/lane ----
// Hb row = 4 heads x 64 feat bf16 = 512B; wave loads 1024B/iter = 2 edge rows.
// lane: slot = lane>>5 (edge), head = (lane>>3)&3, f0 = (lane&7)*8.
__global__ __launch_bounds__(256) void k_agg1(
    const int* __restrict__ rowptr, const int* __restrict__ csr,
    const ushort_t* __restrict__ Hb, const float* __restrict__ als,
    const float* __restrict__ ald, const float* __restrict__ bias,
    ushort_t* __restrict__ OutB)
{
    int w = threadIdx.x >> 6, lane = threadIdx.x & 63;
    int dst = blockIdx.x * 4 + w;
    if (dst >= NN) return;
    const int slot = lane >> 5;
    const int head = (lane >> 3) & 3;
    const int f0   = (lane & 7) * 8;
    const int beg = rowptr[dst], end = rowptr[dst + 1];
    const float adst = ald[dst * 4 + head];

    int  i      = beg;
    int  e_idx  = i + slot;
    bool valid  = e_idx < end;
    int  src    = csr[valid ? e_idx : (end - 1)];
    float as_v  = als[src * 4 + head];
    us8_t xv    = *(const us8_t*)&Hb[(size_t)src * 256 + head * 64 + f0];

    float m = -1e30f, s = 0.f;
    float acc[8] = {};
    while (true) {
        int inext = i + 2;
        bool more = inext < end;
        int src2 = 0; float as2 = 0.f; us8_t xv2 = {};
        bool valid2 = false;
        if (more) {                                    // 1-iter-ahead prefetch
            int e2 = inext + slot;
            valid2 = e2 < end;
            src2 = csr[valid2 ? e2 : (end - 1)];
            as2  = als[src2 * 4 + head];
            xv2  = *(const us8_t*)&Hb[(size_t)src2 * 256 + head * 64 + f0];
        }
        float e = as_v + adst;
        e = (e > 0.f) ? e : NEG * e;                   // leaky_relu
        if (!valid) e = -1e30f;
        float eo = __shfl_xor(e, 32);                  // other slot, same head/f
        float mn = fmaxf(m, fmaxf(e, eo));
        float sc = __expf(m - mn);
        float pr = __expf(e - mn);                     // per-lane partial (own slot)
        s = s * sc + pr;
#pragma unroll
        for (int j = 0; j < 8; j++)
            acc[j] = acc[j] * sc + pr * bf2f((ushort_t)xv[j]);
        m = mn;
        if (!more) break;
        i = inext; src = src2; as_v = as2; xv = xv2; valid = valid2;
    }
    // combine the two slots (sc used wave-consistent mn, so partials just add)
    s += __shfl_xor(s, 32);
#pragma unroll
    for (int j = 0; j < 8; j++) acc[j] += __shfl_xor(acc[j], 32);
    if (lane < 32) {
        us8_t o8;
#pragma unroll
        for (int j = 0; j < 8; j++) {
            float o = acc[j] / (s + 1e-16f) + bias[head * 64 + f0 + j];
            o = (o > 0.f) ? o : 0.f;                   // relu
            o8[j] = f2bf(o);
        }
        *(us8_t*)&OutB[(size_t)dst * 256 + head * 64 + f0] = o8;
    }
}

// ---- layer-2 aggregation: ONE wave per dst, 1 head, 4 edges/iter, 8B/lane ----
// lane: slot = lane>>4 (edge), f0 = (lane&15)*4.
__global__ __launch_bounds__(256) void k_agg2(
    const int* __restrict__ rowptr, const int* __restrict__ csr,
    const ushort_t* __restrict__ Hb, const float* __restrict__ als,
    const float* __restrict__ ald, const float* __restrict__ bias,
    float* __restrict__ OutF)
{
    int w = threadIdx.x >> 6, lane = threadIdx.x & 63;
    int dst = blockIdx.x * 4 + w;
    if (dst >= NN) return;
    const int slot = lane >> 4;
    const int f0   = (lane & 15) * 4;
    const int beg = rowptr[dst], end = rowptr[dst + 1];
    const float adst = ald[dst];

    int  i     = beg;
    int  e_idx = i + slot;
    bool valid = e_idx < end;
    int  src   = csr[valid ? e_idx : (end - 1)];
    float as_v = als[src];
    ushort4 xv = *(const ushort4*)&Hb[(size_t)src * 64 + f0];

    float m = -1e30f, s = 0.f;
    float acc[4] = {};
    while (true) {
        int inext = i + 4;
        bool more = inext < end;
        int src2 = 0; float as2 = 0.f; ushort4 xv2 = make_ushort4(0, 0, 0, 0);
        bool valid2 = false;
        if (more) {
            int e2 = inext + slot;
            valid2 = e2 < end;
            src2 = csr[valid2 ? e2 : (end - 1)];
            as2  = als[src2];
            xv2  = *(const ushort4*)&Hb[(size_t)src2 * 64 + f0];
        }
        float e = as_v + adst;
        e = (e > 0.f) ? e : NEG * e;
        if (!valid) e = -1e30f;
        float e1 = fmaxf(e, __shfl_xor(e, 16));
        float e2m = fmaxf(e1, __shfl_xor(e1, 32));     // max over 4 slots
        float mn = fmaxf(m, e2m);
        float sc = __expf(m - mn);
        float pr = __expf(e - mn);                     // per-lane partial
        s = s * sc + pr;
        acc[0] = acc[0] * sc + pr * bf2f(xv.x);
        acc[1] = acc[1] * sc + pr * bf2f(xv.y);
        acc[2] = acc[2] * sc + pr * bf2f(xv.z);
        acc[3] = acc[3] * sc + pr * bf2f(xv.w);
        m = mn;
        if (!more) break;
        i = inext; src = src2; as_v = as2; xv = xv2; valid = valid2;
    }
    s += __shfl_xor(s, 16); s += __shfl_xor(s, 32);
#pragma unroll
    for (int j = 0; j < 4; j++) {
        acc[j] += __shfl_xor(acc[j], 16);
        acc[j] += __shfl_xor(acc[j], 32);
    }
    if (lane < 16) {
        float4 o;
        float* op = &o.x;
#pragma unroll
        for (int j = 0; j < 4; j++) {
            float v = acc[j] / (s + 1e-16f) + bias[f0 + j];
            op[j] = (v > 0.f) ? v : 0.f;
        }
        *(float4*)&OutF[(size_t)dst * 64 + f0] = o;
    }
}

// ---------------- fused mean-pool (sorted batch, no atomics) + classifier --------
__global__ void k_pool_final(const float* __restrict__ out2, const int* __restrict__ batch,
                             const float* __restrict__ Wl, const float* __restrict__ bl,
                             float* __restrict__ out)
{
    int g = blockIdx.x;
    int lo, hi;
    { int a = 0, b = NN; while (a < b) { int mm = (a + b) >> 1; if (batch[mm] < g) a = mm + 1; else b = mm; } lo = a; }
    { int a = lo, b = NN; while (a < b) { int mm = (a + b) >> 1; if (batch[mm] < g + 1) a = mm + 1; else b = mm; } hi = a; }
    int t = threadIdx.x, c = t & 63, r = t >> 6;
    float s = 0.f;
    for (int n = lo + r; n < hi; n += 4) s += out2[(size_t)n * 64 + c];
    __shared__ float red[256];
    red[t] = s;
    __syncthreads();
    if (t < 64) {
        float p = red[t] + red[t + 64] + red[t + 128] + red[t + 192];
        int cntv = hi - lo;
        p /= (float)(cntv > 0 ? cntv : 1);
        float r0 = p * Wl[t * 2 + 0];
        float r1 = p * Wl[t * 2 + 1];
#pragma unroll
        for (int off = 32; off > 0; off >>= 1) {
            r0 += __shfl_xor(r0, off);
            r1 += __shfl_xor(r1, off);
        }
        if (t == 0) {
            out[g * 2 + 0] = r0 + bl[0];
            out[g * 2 + 1] = r1 + bl[1];
        }
    }
}

extern "C" void kernel_launch(void* const* d_in, const int* in_sizes, int n_in,
                              void* d_out, int out_size, void* d_ws, size_t ws_size,
                              hipStream_t stream)
{
    const float* x    = (const float*)d_in[0];
    const int*   ei   = (const int*)  d_in[1];
    const int*   batch= (const int*)  d_in[2];
    const float* W1   = (const float*)d_in[3];
    const float* as1  = (const float*)d_in[4];
    const float* ad1  = (const float*)d_in[5];
    const float* b1   = (const float*)d_in[6];
    const float* W2   = (const float*)d_in[7];
    const float* as2  = (const float*)d_in[8];
    const float* ad2  = (const float*)d_in[9];
    const float* b2   = (const float*)d_in[10];
    const float* Wl   = (const float*)d_in[11];
    const float* bl   = (const float*)d_in[12];
    float* out = (float*)d_out;

    // ---- workspace carve-up ----
    int*   deg    = (int*)d_ws;                       // 50048
    int*   cursor = deg + 50048;                      // 50048
    int*   part   = cursor + 50048;                   // 256
    int*   rowptr = part + 256;                       // 50064
    int*   csr    = rowptr + 50064;                   // 850048
    ushort_t* xb  = (ushort_t*)(csr + 850048);        // 50048*512
    ushort_t* Wt1 = xb + (size_t)50048 * 512;         // 256*512
    ushort_t* Wt2 = Wt1 + 131072;                     // 64*256
    ushort_t* h1b = Wt2 + 16384;                      // 50000*256
    float* al1s   = (float*)(h1b + (size_t)50000 * 256); // 200000
    float* al1d   = al1s + 200000;
    float* al2s   = al1d + 200000;                    // 50000
    float* al2d   = al2s + 50000;
    // aliases inside xb (dead after GEMM1):
    ushort_t* out1b = xb;                             // 50176*256
    ushort_t* h2b   = xb + 13000000;                  // 50000*64
    float*    out2  = (float*)(xb + 16400000);        // 50000*64 floats

    hipMemsetAsync(deg, 0, 2 * 50048 * sizeof(int), stream);   // deg + cursor

    // CSR build
    k_deg       <<<(NET + 255) / 256, 256, 0, stream>>>(ei, deg);
    k_scan_part <<<196, 256, 0, stream>>>(deg, part);
    k_scan_top  <<<1,   256, 0, stream>>>(part, 196);
    k_scan_apply<<<196, 256, 0, stream>>>(deg, part, rowptr);
    k_fill      <<<(NET + 255) / 256, 256, 0, stream>>>(ei, rowptr, cursor, csr);

    // bf16 casts
    k_cast_x<<<(50048 * 128 + 255) / 256, 256, 0, stream>>>(x, xb);
    k_cast_wt<500, 512, 256><<<(256 * 512 + 255) / 256, 256, 0, stream>>>(W1, Wt1);
    k_cast_wt<256, 256, 64> <<<(64 * 256 + 255) / 256, 256, 0, stream>>>(W2, Wt2);

    // layer 1: M=50048(pad), N=256, K=512(pad); tile 128x128, 2x2 waves
    k_mfma<512, 512, 128, 128, 2, 256, 4><<<dim3(2, 391), 256, 0, stream>>>(
        xb, Wt1, as1, ad1, h1b, al1s, al1d);
    k_agg1<<<(NN + 3) / 4, 256, 0, stream>>>(rowptr, csr, h1b, al1s, al1d, b1, out1b);
    // zero pad rows 50000..50175 of out1b for GEMM2
    hipMemsetAsync(out1b + (size_t)50000 * 256, 0, (size_t)176 * 256 * sizeof(ushort_t), stream);

    // layer 2: M=50176(pad), N=64, K=256; tile 256x64, 4x1 waves
    k_mfma<256, 256, 256, 64, 4, 64, 1><<<dim3(1, 196), 256, 0, stream>>>(
        out1b, Wt2, as2, ad2, h2b, al2s, al2d);
    k_agg2<<<(NN + 3) / 4, 256, 0, stream>>>(rowptr, csr, h2b, al2s, al2d, b2, out2);

    // fused pool + classifier
    k_pool_final<<<NG, 256, 0, stream>>>(out2, batch, Wl, bl, out);
}